// Round 6
// baseline (319.903 us; speedup 1.0000x reference)
//
// GroupedSubMConv3d conv_main v4 — cross-tile software pipeline + XCD swizzle
#include <hip/hip_runtime.h>
#include <hip/hip_fp16.h>

#define NVOX 400000
#define KVOL 27
#define CTOT 64
#define NTILES (NVOX / 16)     // 25000 exact
#define NPAIR 14               // 27 offsets -> 14 pairs (last half-padded)
#define TPB 10                 // tiles per persistent block
#define NBLOCKS (NTILES / TPB) // 2500 exact
#define WFRAG_HALVES (4 * NPAIR * 64 * 8)    // 28672 f16 = 57344 B

// ---------------- ws layout ----------------
// featH : _Float16[NVOX*64]   offset 0           (51,200,000 B)
// wfrag : _Float16[28672]     offset 51,200,000  (57,344 B)
#define FEATH_OFF 0
#define WFRAG_OFF 51200000

typedef __attribute__((ext_vector_type(8))) _Float16 half8;
typedef __attribute__((ext_vector_type(4))) float float4v;

// feat fp32 -> fp16, 8 elements per thread
__global__ void cvt_feat_kernel(const float* __restrict__ f, _Float16* __restrict__ fh) {
    int t = blockIdx.x * blockDim.x + threadIdx.x;
    const int total = NVOX * CTOT / 8;   // 3,200,000 threads
    if (t >= total) return;
    const float4* fp = (const float4*)f + (size_t)t * 2;
    float4 a = fp[0], b = fp[1];
    union { _Float16 h[8]; uint4 u; } r;
    r.h[0] = (_Float16)a.x; r.h[1] = (_Float16)a.y;
    r.h[2] = (_Float16)a.z; r.h[3] = (_Float16)a.w;
    r.h[4] = (_Float16)b.x; r.h[5] = (_Float16)b.y;
    r.h[6] = (_Float16)b.z; r.h[7] = (_Float16)b.w;
    ((uint4*)fh)[t] = r.u;
}

// weight[g][ko][ci][co] fp32 -> B-fragment layout f16:
// wfrag[g][p][lane][j] = w[g][2p + (quad>>1)][ci=(quad&1)*8+j][co=lane&15], quad=lane>>4
// ko >= 27 (padded pair-13 second slot) -> 0.0
__global__ void cvt_w_kernel(const float* __restrict__ w, _Float16* __restrict__ wf) {
    int t = blockIdx.x * blockDim.x + threadIdx.x;
    if (t >= WFRAG_HALVES) return;
    int j = t & 7;
    int l = (t >> 3) & 63;
    int gp = t >> 9;            // 0..55
    int p = gp % NPAIR;
    int g = gp / NPAIR;
    int co = l & 15;
    int quad = l >> 4;
    int ko = 2 * p + (quad >> 1);
    int ci = (quad & 1) * 8 + j;
    float val = (ko < KVOL) ? w[((g * KVOL + ko) * 16 + ci) * 16 + co] : 0.f;
    wf[t] = (_Float16)val;
}

__global__ __launch_bounds__(256, 2) void conv_main_kernel(
        const _Float16* __restrict__ fh,
        const uint4*    __restrict__ wfrag,
        const float*    __restrict__ bias,
        const int*      __restrict__ nb,
        float* __restrict__ out) {
    __shared__ int s_nb[2][16 * KVOL];   // linear [tilebuf][432]
    const int t = threadIdx.x;
    const int lane = t & 63;
    const int g = t >> 6;                // wave index = group
    const int v = lane & 15;             // voxel within tile (A-frag row m)
    const int quad = lane >> 4;
    const int q2 = quad >> 1;            // which offset of the pair
    const int half = quad & 1;           // which 8-ci half
    const int co = lane & 15;

    // bijective XCD swizzle (m204): consecutive resident blocks on one XCD
    // handle spatially-adjacent tiles -> neighbor gather rows share that XCD's L2
    {
        // nothing extra
    }
    const int q_ = NBLOCKS / 8, r_ = NBLOCKS % 8;   // 312, 4
    const int xcd = blockIdx.x % 8;
    const int chunk = blockIdx.x / 8;
    const int wgid = (xcd < r_ ? xcd * (q_ + 1) : r_ * (q_ + 1) + (xcd - r_) * q_) + chunk;
    const int tile0 = wgid * TPB;

    // B-fragments resident in registers, loaded ONCE per block
    uint4 wB[NPAIR];
#pragma unroll
    for (int p = 0; p < NPAIR; ++p)
        wB[p] = wfrag[(g * NPAIR + p) * 64 + lane];

    const _Float16* fbase = fh + g * 16 + half * 8;
    const float breg = bias[g * 16 + co];
    const int vb = v * KVOL;

// stage tile's 432 nb dwords linearly into buffer b
#define STAGE(b, tile)                                              \
    {                                                               \
        const int* src = nb + (size_t)(tile) * (16 * KVOL);         \
        for (int j = t; j < 16 * KVOL; j += 256)                    \
            s_nb[(b)][j] = src[j];                                  \
    }

// read 14 pair-indices for this lane from buffer b, issue masked gathers into dst
#define GATHER(dst, b)                                              \
    {                                                               \
        int ix[NPAIR];                                              \
        _Pragma("unroll")                                           \
        for (int p = 0; p < NPAIR - 1; ++p)                         \
            ix[p] = s_nb[(b)][vb + 2 * p + q2];                     \
        ix[NPAIR - 1] = (q2 == 0) ? s_nb[(b)][vb + 26] : -1;        \
        _Pragma("unroll")                                           \
        for (int p = 0; p < NPAIR; ++p) {                           \
            uint4 z = {0u, 0u, 0u, 0u};                             \
            dst[p] = z;                                             \
            if (ix[p] >= 0)                                         \
                dst[p] = *(const uint4*)(fbase + (size_t)ix[p] * CTOT); \
        }                                                           \
    }

    // ---- pipeline prologue: tile 0 ----
    STAGE(0, tile0);
    __syncthreads();
    uint4 aA[NPAIR];
    GATHER(aA, 0);

#pragma unroll
    for (int tt = 0; tt < TPB; ++tt) {
        uint4 aB[NPAIR];
        if (tt + 1 < TPB) {
            // prefetch next tile: buffer (tt+1)&1 was last READ two iterations
            // ago (one barrier in between) -> single barrier per tile is safe
            STAGE((tt + 1) & 1, tile0 + tt + 1);
            __syncthreads();
            GATHER(aB, (tt + 1) & 1);
        }
        // pin: next tile's gathers issued before this tile's MFMA cluster
        __builtin_amdgcn_sched_barrier(0);

        float4v acc0 = {0.f, 0.f, 0.f, 0.f};
        float4v acc1 = {0.f, 0.f, 0.f, 0.f};
#pragma unroll
        for (int p = 0; p < NPAIR; p += 2) {
            acc0 = __builtin_amdgcn_mfma_f32_16x16x32_f16(
                __builtin_bit_cast(half8, aA[p]),
                __builtin_bit_cast(half8, wB[p]), acc0, 0, 0, 0);
            acc1 = __builtin_amdgcn_mfma_f32_16x16x32_f16(
                __builtin_bit_cast(half8, aA[p + 1]),
                __builtin_bit_cast(half8, wB[p + 1]), acc1, 0, 0, 0);
        }

        // C/D layout: col(co) = lane&15, row(voxel) = quad*4 + r
        float* ob = out + ((size_t)((tile0 + tt) * 16 + quad * 4)) * CTOT + g * 16 + co;
#pragma unroll
        for (int r = 0; r < 4; ++r)
            ob[(size_t)r * CTOT] = acc0[r] + acc1[r] + breg;

        if (tt + 1 < TPB) {
#pragma unroll
            for (int p = 0; p < NPAIR; ++p)
                aA[p] = aB[p];
        }
    }
#undef STAGE
#undef GATHER
}

extern "C" void kernel_launch(void* const* d_in, const int* in_sizes, int n_in,
                              void* d_out, int out_size, void* d_ws, size_t ws_size,
                              hipStream_t stream) {
    const float* features = (const float*)d_in[0];
    const float* weight   = (const float*)d_in[1];
    const float* bias     = (const float*)d_in[2];
    const int*   nb       = (const int*)d_in[3];
    float* out = (float*)d_out;

    char* ws = (char*)d_ws;
    _Float16* featH = (_Float16*)(ws + FEATH_OFF);
    _Float16* wf    = (_Float16*)(ws + WFRAG_OFF);

    cvt_feat_kernel<<<(NVOX * CTOT / 8 + 255) / 256, 256, 0, stream>>>(features, featH);
    cvt_w_kernel<<<(WFRAG_HALVES + 255) / 256, 256, 0, stream>>>(weight, wf);
    conv_main_kernel<<<NBLOCKS, 256, 0, stream>>>(featH, (const uint4*)wf, bias, nb, out);
}

// Round 7
// 300.979 us; speedup vs baseline: 1.0629x; 1.0629x over previous
//
// GroupedSubMConv3d v5 — v3.1 core + NT streaming hints + fused cvt + linear s_nb + XCD swizzle
#include <hip/hip_runtime.h>
#include <hip/hip_fp16.h>

#define NVOX 400000
#define KVOL 27
#define CTOT 64
#define NTILES (NVOX / 16)     // 25000 exact
#define NPAIR 14               // 27 offsets -> 14 pairs (last half-padded)
#define TPB 10                 // tiles per persistent block
#define NBLOCKS (NTILES / TPB) // 2500 exact
#define WFRAG_HALVES (4 * NPAIR * 64 * 8)     // 28672 f16 = 57344 B
#define FEAT_BLOCKS (NVOX * CTOT / 8 / 256)   // 12500 exact
#define W_BLOCKS (WFRAG_HALVES / 256)         // 112 exact

// ---------------- ws layout ----------------
// featH : _Float16[NVOX*64]   offset 0           (51,200,000 B)
// wfrag : _Float16[28672]     offset 51,200,000  (57,344 B)
#define FEATH_OFF 0
#define WFRAG_OFF 51200000

typedef __attribute__((ext_vector_type(8))) _Float16 half8;
typedef __attribute__((ext_vector_type(4))) float float4v;

// Fused convert kernel: blocks [0,12500) do feat fp32->fp16 (NT reads of the
// 102MB fp32 stream, cached writes so featH lands in L2/L3 for conv to hit);
// blocks [12500,12612) build the weight B-fragment table.
__global__ void cvt_fused_kernel(const float* __restrict__ f,
                                 const float* __restrict__ w,
                                 _Float16* __restrict__ fh,
                                 _Float16* __restrict__ wf) {
    const int b = blockIdx.x;
    if (b < FEAT_BLOCKS) {
        const int t = b * 256 + threadIdx.x;     // < 3,200,000
        const float4v* fp = (const float4v*)f + (size_t)t * 2;
        float4v a = __builtin_nontemporal_load(fp);
        float4v c = __builtin_nontemporal_load(fp + 1);
        union { _Float16 h[8]; uint4 u; } r;
        r.h[0] = (_Float16)a[0]; r.h[1] = (_Float16)a[1];
        r.h[2] = (_Float16)a[2]; r.h[3] = (_Float16)a[3];
        r.h[4] = (_Float16)c[0]; r.h[5] = (_Float16)c[1];
        r.h[6] = (_Float16)c[2]; r.h[7] = (_Float16)c[3];
        ((uint4*)fh)[t] = r.u;                   // cached: conv re-reads this
    } else {
        // weight[g][ko][ci][co] fp32 -> B-frag f16:
        // wf[g][p][lane][j] = w[g][2p+(quad>>1)][ci=(quad&1)*8+j][co=lane&15]
        // ko >= 27 (pair-13 second slot) -> 0.0
        const int t = (b - FEAT_BLOCKS) * 256 + threadIdx.x;
        if (t < WFRAG_HALVES) {
            int j = t & 7;
            int l = (t >> 3) & 63;
            int gp = t >> 9;            // 0..55
            int p = gp % NPAIR;
            int g = gp / NPAIR;
            int co = l & 15;
            int quad = l >> 4;
            int ko = 2 * p + (quad >> 1);
            int ci = (quad & 1) * 8 + j;
            float val = (ko < KVOL) ? w[((g * KVOL + ko) * 16 + ci) * 16 + co] : 0.f;
            wf[t] = (_Float16)val;
        }
    }
}

__global__ __launch_bounds__(256) void conv_main_kernel(
        const _Float16* __restrict__ fh,
        const uint4*    __restrict__ wfrag,
        const float*    __restrict__ bias,
        const int*      __restrict__ nb,
        float* __restrict__ out) {
    __shared__ int s_nb[16 * KVOL];      // linear [432]
    const int t = threadIdx.x;
    const int lane = t & 63;
    const int g = t >> 6;                // wave index = group
    const int v = lane & 15;             // voxel within tile (A-frag row m)
    const int quad = lane >> 4;
    const int q2 = quad >> 1;            // which offset of the pair
    const int half = quad & 1;           // which 8-ci half
    const int co = lane & 15;
    const int vb = v * KVOL;

    // bijective XCD swizzle (m204): consecutive tile-chunks share an XCD's L2,
    // so spatial-neighbor gather rows get temporal reuse within 4MB
    const int q_ = NBLOCKS / 8, r_ = NBLOCKS % 8;   // 312, 4
    const int xcd = blockIdx.x & 7;
    const int chunk = blockIdx.x >> 3;
    const int wgid = (xcd < r_ ? xcd * (q_ + 1) : r_ * (q_ + 1) + (xcd - r_) * q_) + chunk;
    const int tile0 = wgid * TPB;

    // B-fragments resident in registers, loaded ONCE per block (amortized 10x)
    uint4 wB[NPAIR];
#pragma unroll
    for (int p = 0; p < NPAIR; ++p)
        wB[p] = wfrag[(g * NPAIR + p) * 64 + lane];

    const _Float16* fbase = fh + g * 16 + half * 8;
    const float breg = bias[g * 16 + co];

    for (int tt = 0; tt < TPB; ++tt) {
        const int tile = tile0 + tt;

        // protect s_nb against overwrite while prev tile's waves still read it
        __syncthreads();
        // NT stage: nb dwords are read exactly once -> don't pollute L2/L3
        const int* src = nb + (size_t)tile * (16 * KVOL);
        for (int j = t; j < 16 * KVOL; j += 256)
            s_nb[j] = __builtin_nontemporal_load(src + j);
        __syncthreads();

        // all 14 pair-indices up front (conflict-free: 27 coprime to 32 banks)
        int ix[NPAIR];
#pragma unroll
        for (int p = 0; p < NPAIR - 1; ++p)
            ix[p] = s_nb[vb + 2 * p + q2];
        ix[NPAIR - 1] = (q2 == 0) ? s_nb[vb + 26] : -1;

        // exec-masked gathers: inactive lanes issue/return nothing; CACHED
        // (featH rows are the only reusable stream - keep them in L2/L3)
        uint4 a[NPAIR];
#pragma unroll
        for (int p = 0; p < NPAIR; ++p) {
            uint4 z = {0u, 0u, 0u, 0u};
            a[p] = z;
            if (ix[p] >= 0)
                a[p] = *(const uint4*)(fbase + (size_t)ix[p] * CTOT);
        }
        // keep all gathers issued before the MFMA cluster
        __builtin_amdgcn_sched_barrier(0);

        // two independent accumulator chains
        float4v acc0 = {0.f, 0.f, 0.f, 0.f};
        float4v acc1 = {0.f, 0.f, 0.f, 0.f};
#pragma unroll
        for (int p = 0; p < NPAIR; p += 2) {
            acc0 = __builtin_amdgcn_mfma_f32_16x16x32_f16(
                __builtin_bit_cast(half8, a[p]),
                __builtin_bit_cast(half8, wB[p]), acc0, 0, 0, 0);
            acc1 = __builtin_amdgcn_mfma_f32_16x16x32_f16(
                __builtin_bit_cast(half8, a[p + 1]),
                __builtin_bit_cast(half8, wB[p + 1]), acc1, 0, 0, 0);
        }

        // C/D layout: col(co)=lane&15, row(voxel)=quad*4+r. NT stores:
        // output is write-once -> bypass L2/L3, keep them for gathers.
        float* ob = out + ((size_t)(tile * 16 + quad * 4)) * CTOT + g * 16 + co;
#pragma unroll
        for (int r = 0; r < 4; ++r)
            __builtin_nontemporal_store(acc0[r] + acc1[r] + breg, ob + (size_t)r * CTOT);
    }
}

extern "C" void kernel_launch(void* const* d_in, const int* in_sizes, int n_in,
                              void* d_out, int out_size, void* d_ws, size_t ws_size,
                              hipStream_t stream) {
    const float* features = (const float*)d_in[0];
    const float* weight   = (const float*)d_in[1];
    const float* bias     = (const float*)d_in[2];
    const int*   nb       = (const int*)d_in[3];
    float* out = (float*)d_out;

    char* ws = (char*)d_ws;
    _Float16* featH = (_Float16*)(ws + FEATH_OFF);
    _Float16* wf    = (_Float16*)(ws + WFRAG_OFF);

    cvt_fused_kernel<<<FEAT_BLOCKS + W_BLOCKS, 256, 0, stream>>>(features, weight, featH, wf);
    conv_main_kernel<<<NBLOCKS, 256, 0, stream>>>(featH, (const uint4*)wf, bias, nb, out);
}